// Round 9
// baseline (386.320 us; speedup 1.0000x reference)
//
#include <hip/hip_runtime.h>
#include <hip/hip_bf16.h>
#include <stdint.h>

#define B_ 4
#define S_ 2048
#define D_ 1024
#define F_ 4096
#define E_ 8
#define CAP_ 320
#define BS_ (B_*S_)      // 8192 tokens
#define MPE 1280         // B_*CAP_ rows per expert

typedef unsigned short u16;
typedef __attribute__((ext_vector_type(8))) short bf16x8;
typedef __attribute__((ext_vector_type(4))) float f32x4;
typedef __attribute__((ext_vector_type(4))) unsigned short u16x4;
typedef __attribute__((ext_vector_type(8))) unsigned short u16x8;

__device__ __forceinline__ u16 f2bf(float f) {
  union { float f; uint32_t u; } v; v.f = f;
  uint32_t r = (v.u + 0x7FFFu + ((v.u >> 16) & 1u)) >> 16;
  return (u16)r;
}

__device__ __forceinline__ void gload16(const void* g, void* l) {
  __builtin_amdgcn_global_load_lds(
      (const __attribute__((address_space(1))) uint32_t*)g,
      (__attribute__((address_space(3))) uint32_t*)l, 16, 0, 0);
}

// ---------------------------------------------------------------------------
// Transpose+convert block (256 threads): W[e][K][N] f32 -> WT[e][N][K] bf16.
// Tile = 128 K-rows x 64 N-cols. Needs >= 128*65*4 B (33.3 KiB) of LDS.
// ---------------------------------------------------------------------------
__device__ __forceinline__ void transpose_block256(
    const float* __restrict__ W, u16* __restrict__ WT,
    const int K, const int N, const int bid, void* ldsraw)
{
  float (*tile)[65] = (float(*)[65])ldsraw;
  const int tk = K >> 7, tn = N >> 6;
  const int e = bid / (tk * tn), r = bid % (tk * tn);
  const int k0 = (r / tn) << 7, n0 = (r % tn) << 6;
  const float* We = W + (size_t)e * K * N;
  u16* WTe = WT + (size_t)e * N * K;
  const int t = threadIdx.x;
  // load: row fr = t>>1 (0..127), cols (t&1)*32 .. +31  (8 x float4)
  const int fr = t >> 1, c0 = (t & 1) * 32;
#pragma unroll
  for (int j = 0; j < 8; ++j) {
    const float4 v = *(const float4*)(We + (size_t)(k0 + fr) * N + n0 + c0 + j * 4);
    tile[fr][c0 + j*4 + 0] = v.x; tile[fr][c0 + j*4 + 1] = v.y;
    tile[fr][c0 + j*4 + 2] = v.z; tile[fr][c0 + j*4 + 3] = v.w;
  }
  __syncthreads();
  // store: n-row nr = t>>2 (0..63), k-cols (t&3)*32 .. +31 (4 x u16x8)
  const int nr = t >> 2, kk0 = (t & 3) * 32;
  u16* dst = WTe + (size_t)(n0 + nr) * K + k0 + kk0;
#pragma unroll
  for (int h = 0; h < 4; ++h) {
    u16x8 o;
#pragma unroll
    for (int j = 0; j < 8; ++j) o[j] = f2bf(tile[kk0 + h*8 + j][nr]);
    *(u16x8*)(dst + h * 8) = o;
  }
}

__global__ __launch_bounds__(256) void transpose_kernel(
    const float* __restrict__ W, u16* __restrict__ WT, const int K, const int N)
{
  __shared__ __align__(16) float tile[128][65];
  transpose_block256(W, WT, K, N, blockIdx.x, (void*)tile);
}

// ---------------------------------------------------------------------------
// Prep: blocks [0,twiT) = wi transpose; rest = router (4 tokens/block,
// wave per token, f64 accum). Router writes logits, maxp, eidx only.
// ---------------------------------------------------------------------------
__global__ __launch_bounds__(256) void prep_kernel(
    const float* __restrict__ hs, const float* __restrict__ rw,
    const float* __restrict__ wi, u16* __restrict__ wT,
    float* __restrict__ logits, float* __restrict__ maxp,
    int* __restrict__ eidx, const int twiT)
{
  __shared__ __align__(16) float tile[128][65];
  if ((int)blockIdx.x < twiT) {
    transpose_block256(wi, wT, D_, F_, blockIdx.x, (void*)tile);
    return;
  }
  const int wv = threadIdx.x >> 6, l = threadIdx.x & 63;
  const int token = (blockIdx.x - twiT) * 4 + wv;
  const float* row = hs + (size_t)token * D_;
  const float4* rw4 = (const float4*)rw;

  double acc0=0, acc1=0, acc2=0, acc3=0, acc4=0, acc5=0, acc6=0, acc7=0;
#pragma unroll
  for (int j = 0; j < 4; ++j) {
    const int d4 = l + j * 64;
    const float4 v = ((const float4*)row)[d4];
#pragma unroll
    for (int c = 0; c < 4; ++c) {
      const int d = d4 * 4 + c;
      const float x = (&v.x)[c];
      const float4 w0 = rw4[d * 2];
      const float4 w1 = rw4[d * 2 + 1];
      acc0 += (double)x * (double)w0.x;
      acc1 += (double)x * (double)w0.y;
      acc2 += (double)x * (double)w0.z;
      acc3 += (double)x * (double)w0.w;
      acc4 += (double)x * (double)w1.x;
      acc5 += (double)x * (double)w1.y;
      acc6 += (double)x * (double)w1.z;
      acc7 += (double)x * (double)w1.w;
    }
  }
  double acc[E_] = {acc0, acc1, acc2, acc3, acc4, acc5, acc6, acc7};
#pragma unroll
  for (int e = 0; e < E_; ++e) {
#pragma unroll
    for (int off = 32; off; off >>= 1)
      acc[e] += __shfl_xor(acc[e], off);
  }
  if (l == 0) {
    float lg[E_];
#pragma unroll
    for (int e = 0; e < E_; ++e) lg[e] = (float)acc[e];
    float lmax = lg[0]; int am = 0;
#pragma unroll
    for (int e = 1; e < E_; ++e) { if (lg[e] > lmax) { lmax = lg[e]; am = e; } }
    float sum = 0.f;
#pragma unroll
    for (int e = 0; e < E_; ++e) sum += expf(lg[e] - lmax);
#pragma unroll
    for (int e = 0; e < E_; ++e) logits[(size_t)token * E_ + e] = lg[e];
    maxp[token] = 1.0f / sum;
    eidx[token] = am;
  }
}

// ---------------------------------------------------------------------------
// Capacity scan: one block per (b,e). Also: tok init (-1), eout, and
// out rows for DROPPED tokens (out = maxp * hs).
// ---------------------------------------------------------------------------
__global__ __launch_bounds__(256) void scan_kernel(
    const int* __restrict__ eidx, int* __restrict__ tok,
    float* __restrict__ eout, const float* __restrict__ hs,
    const float* __restrict__ maxp, float* __restrict__ out)
{
  const int b = blockIdx.x >> 3, e = blockIdx.x & 7;
  __shared__ int wsum[4];
  const int tid = threadIdx.x, wv = tid >> 6, l = tid & 63;
  for (int i = tid; i < CAP_; i += 256) tok[(b * E_ + e) * CAP_ + i] = -1;
  __syncthreads();
  int base = 0;
  for (int ch = 0; ch < S_ / 256; ++ch) {
    const int s = ch * 256 + tid;
    const bool p = (eidx[b * S_ + s] == e);
    const unsigned long long m = __ballot(p);
    const int lp = __popcll(m & ((1ULL << l) - 1ULL));
    if (l == 0) wsum[wv] = __popcll(m);
    __syncthreads();
    int pre = 0, tot = 0;
#pragma unroll
    for (int w = 0; w < 4; ++w) { if (w < wv) pre += wsum[w]; tot += wsum[w]; }
    if (p) {
      const int rank = base + pre + lp;
      if (rank < CAP_) {
        tok[(b * E_ + e) * CAP_ + rank] = s;
        eout[b * S_ + s] = (float)e;
      } else {
        eout[b * S_ + s] = 0.0f;
        const float mp = maxp[b * S_ + s];
        const float4* src = (const float4*)(hs + (size_t)(b * S_ + s) * D_);
        float4* dst = (float4*)(out + (size_t)(b * S_ + s) * D_);
        for (int j = 0; j < D_ / 4; ++j) {
          const float4 vv = src[j];
          float4 o; o.x = vv.x * mp; o.y = vv.y * mp; o.z = vv.z * mp; o.w = vv.w * mp;
          dst[j] = o;
        }
      }
    }
    base += tot;
    __syncthreads();
  }
}

// ---------------------------------------------------------------------------
// Gather routed tokens -> Xg[e][b*CAP+c][D] bf16 (zeros for empty slots)
// ---------------------------------------------------------------------------
__global__ __launch_bounds__(256) void gather_kernel(
    const float* __restrict__ hs, const int* __restrict__ tok,
    u16* __restrict__ Xg)
{
  const int bx = blockIdx.x;
  const int e = bx / MPE, r = bx % MPE;
  const int b = r / CAP_, c = r % CAP_;
  const int t = tok[(b * E_ + e) * CAP_ + c];
  const int d = threadIdx.x * 4;
  u16x4 o;
  if (t >= 0) {
    const float4 vv = *(const float4*)(hs + ((size_t)(b * S_ + t)) * D_ + d);
    o[0] = f2bf(vv.x); o[1] = f2bf(vv.y); o[2] = f2bf(vv.z); o[3] = f2bf(vv.w);
  } else {
    o[0] = 0; o[1] = 0; o[2] = 0; o[3] = 0;
  }
  *(u16x4*)(Xg + (size_t)bx * D_ + d) = o;
}

// ---------------------------------------------------------------------------
// 128x128 grouped GEMM, 256 threads (4 waves, 2x2), 64 KiB LDS dbuf,
// r8-audited read-ahead schedule (counted lgkmcnt, vmcnt(4), 2 bar/tile).
// -> 2 independent blocks/CU for inter-block latency hiding.
// MODE 1: hg = relu(A@B); tail blocks run wo-transpose into DISJOINT WTtr.
// MODE 2: scatter out = maxp * (A@B).
// ---------------------------------------------------------------------------
template<int MODE>
__global__ __launch_bounds__(256, 2) void moe_g(
    const u16* __restrict__ Aall, const u16* __restrict__ Btall,
    u16* __restrict__ hgout, float* __restrict__ out,
    const int* __restrict__ tok, const float* __restrict__ maxp,
    const int K, const int ntn, const int gemm_blocks,
    const float* __restrict__ Wtr, u16* __restrict__ WTtr)
{
  __shared__ __align__(16) u16 lds[2][2][8192];   // [buf][A/B] 64 KiB

  if ((int)blockIdx.x >= gemm_blocks) {
    transpose_block256(Wtr, WTtr, F_, D_, blockIdx.x - gemm_blocks, (void*)lds);
    return;
  }

  const int NT = K >> 6;
  const int cpx = gemm_blocks >> 3;
  const int bid = blockIdx.x;
  const int swzb = (bid & 7) * cpx + (bid >> 3);    // XCD swizzle (grid%8==0)
  const int bpe = 10 * ntn;
  const int e = swzb / bpe, rem = swzb % bpe;
  const int m0 = (rem / ntn) * 128, n0 = (rem % ntn) * 128;
  const int N = ntn * 128;

  const u16* Ae = Aall + (size_t)e * MPE * K;
  const u16* Be = Btall + (size_t)e * N * K;

  const int tid = threadIdx.x;
  const int wv = tid >> 6, l = tid & 63;
  const int wr = wv >> 1, wc = wv & 1;
  const int lr = l & 15, lk = l >> 4;
  const int rswz = ((lr >> 3) & 1) << 4;            // elem XOR for ds_read
  const int gs0 = tid ^ (((tid >> 5) & 1) << 1);    // inverse swizzle on src
  const size_t goff = (size_t)((gs0 >> 2) & 63) * K + (size_t)((gs0 & 3) * 8);
  const int dwoff = wv * 512;                       // wave-uniform LDS elems

  const u16* pA = Ae + (size_t)m0 * K;
  const u16* pB = Be + (size_t)n0 * K;
  const size_t r64 = (size_t)64 * K;                // 64-row stride

  f32x4 acc[4][4];
#pragma unroll
  for (int i = 0; i < 4; ++i)
#pragma unroll
    for (int j = 0; j < 4; ++j) acc[i][j] = (f32x4){0.f, 0.f, 0.f, 0.f};

  bf16x8 faA[2], faB[2], fb[8];

#define BAR() __builtin_amdgcn_s_barrier()
#define LGKMN(n) do { asm volatile("s_waitcnt lgkmcnt(" #n ")" ::: "memory"); \
                      __builtin_amdgcn_sched_barrier(0); } while (0)
#define VMW(n) asm volatile("s_waitcnt vmcnt(" #n ")" ::: "memory")

  // Full 128x64 tile = 4 gloads: units (kk, rowhalf)
#define STAGE_T(dst, rb, tt) do {                                          \
    const u16* s_ = (rb) + goff + (size_t)((tt) * 64);                     \
    gload16(s_,             (dst) + dwoff);          /* kk0 rows 0-63 */   \
    gload16(s_ + r64,       (dst) + 2048 + dwoff);   /* kk0 rows 64-127*/  \
    gload16(s_ + 32,        (dst) + 4096 + dwoff);   /* kk1 rows 0-63 */   \
    gload16(s_ + r64 + 32,  (dst) + 6144 + dwoff);   /* kk1 rows 64-127*/  \
  } while (0)

  // A quarter q (rows wr*64 + q*16 + lr), 2 frags (kk 0,1)
#define READ_AQ(q, p, fa_) do {                                            \
    _Pragma("unroll")                                                      \
    for (int kk = 0; kk < 2; ++kk)                                         \
      fa_[kk] = *(const bf16x8*)&lds[p][0]                                 \
          [(kk*128 + wr*64 + (q)*16 + lr)*32 + ((lk*8) ^ rswz)];           \
  } while (0)

  // Full B tile for this wave: 8 frags (nf 0..3, kk 0..1)
#define READ_B_ALL(p) do {                                                 \
    _Pragma("unroll")                                                      \
    for (int nf = 0; nf < 4; ++nf)                                         \
      _Pragma("unroll")                                                    \
      for (int kk = 0; kk < 2; ++kk)                                       \
        fb[nf*2+kk] = *(const bf16x8*)&lds[p][1]                           \
            [(kk*128 + wc*64 + nf*16 + lr)*32 + ((lk*8) ^ rswz)];          \
  } while (0)

#define MFMA_P(q, fa_) do {                                                \
    __builtin_amdgcn_s_setprio(1);                                         \
    _Pragma("unroll")                                                      \
    for (int nf = 0; nf < 4; ++nf)                                         \
      _Pragma("unroll")                                                    \
      for (int kk = 0; kk < 2; ++kk)                                       \
        acc[q][nf] = __builtin_amdgcn_mfma_f32_16x16x32_bf16(              \
            fa_[kk], fb[nf*2+kk], acc[q][nf], 0, 0, 0);                    \
    __builtin_amdgcn_s_setprio(0);                                         \
  } while (0)

#define DO_T(p, pn, tc) do {                                               \
    READ_AQ(1, p, faB);                                                    \
    if ((tc) + 1 < NT) STAGE_T(&lds[pn][0][0], pA, (tc) + 1);              \
    LGKMN(2); MFMA_P(0, faA);                                              \
    READ_AQ(2, p, faA);                                                    \
    LGKMN(2); MFMA_P(1, faB);                                              \
    BAR();                                                                 \
    READ_AQ(3, p, faB);                                                    \
    if ((tc) + 2 < NT) STAGE_T(&lds[p][1][0], pB, (tc) + 2);               \
    LGKMN(2); MFMA_P(2, faA);                                              \
    LGKMN(0); MFMA_P(3, faB);                                              \
    if ((tc) >= NT - 2) VMW(0); else VMW(4);                               \
    BAR();                                                                 \
    if ((tc) + 1 < NT) { READ_B_ALL(pn); READ_AQ(0, pn, faA); }            \
  } while (0)

  // Prologue: A(0) [4 gl], B(0) [4], B(1) [4]; A(1) staged at t0 slot0.
  STAGE_T(&lds[0][0][0], pA, 0);
  STAGE_T(&lds[0][1][0], pB, 0);
  STAGE_T(&lds[1][1][0], pB, 1);
  VMW(4); BAR();
  READ_B_ALL(0); READ_AQ(0, 0, faA);

  for (int t = 0; t < NT; t += 2) {
    DO_T(0, 1, t);
    DO_T(1, 0, t + 1);
  }

  if (MODE == 1) {
#pragma unroll
    for (int i = 0; i < 4; ++i) {
#pragma unroll
      for (int r = 0; r < 4; ++r) {
        const int grow = m0 + wr * 64 + i * 16 + lk * 4 + r;
        u16* hrow = hgout + ((size_t)e * MPE + grow) * (size_t)N + n0 + wc * 64;
#pragma unroll
        for (int j = 0; j < 4; ++j)
          hrow[j * 16 + lr] = f2bf(fmaxf(acc[i][j][r], 0.0f));
      }
    }
  } else {
#pragma unroll
    for (int i = 0; i < 4; ++i) {
#pragma unroll
      for (int r = 0; r < 4; ++r) {
        const int grow = m0 + wr * 64 + i * 16 + lk * 4 + r;
        const int b = grow / CAP_, c = grow % CAP_;
        const int t = tok[(b * E_ + e) * CAP_ + c];
        if (t >= 0) {
          const float sc = maxp[b * S_ + t];
          float* orow = out + ((size_t)(b * S_ + t)) * D_ + n0 + wc * 64;
#pragma unroll
          for (int j = 0; j < 4; ++j)
            orow[j * 16 + lr] = sc * acc[i][j][r];
        }
      }
    }
  }
#undef BAR
#undef LGKMN
#undef VMW
#undef STAGE_T
#undef READ_AQ
#undef READ_B_ALL
#undef MFMA_P
#undef DO_T
}

// ---------------------------------------------------------------------------
extern "C" void kernel_launch(void* const* d_in, const int* in_sizes, int n_in,
                              void* d_out, int out_size, void* d_ws, size_t ws_size,
                              hipStream_t stream)
{
  const float* hs = (const float*)d_in[0];
  const float* rw = (const float*)d_in[1];
  const float* wi = (const float*)d_in[2];
  const float* wo = (const float*)d_in[3];

  float* out    = (float*)d_out;
  float* logits = out + (size_t)BS_ * D_;
  float* eout   = logits + (size_t)BS_ * E_;

  uint8_t* ws = (uint8_t*)d_ws;
  int*   tok  = (int*)(ws + 0);                 //   40,960 B
  float* maxp = (float*)(ws + 40960);           //   32,768 B
  int*   eidx = (int*)(ws + 73728);             //   32,768 B
  u16*   Xg   = (u16*)(ws + 131072);            // 20,971,520 B
  u16*   hg   = (u16*)(ws + 21102592);          // 83,886,080 B
  u16*   wiT  = (u16*)(ws + 104988672);         // 67,108,864 B
  if (ws_size < 172097536ULL) return;
  const bool big = ws_size >= 239206400ULL;
  u16* woT = big ? (u16*)(ws + 172097536) : wiT;

  const int twiT = E_ * (D_ / 128) * (F_ / 64);  // 4096 wi-transpose blocks
  const int twoT = E_ * (F_ / 128) * (D_ / 64);  // 4096 wo-transpose blocks
  const int g1 = E_ * (MPE / 128) * (F_ / 128);  // 2560 GEMM1 blocks
  const int g2 = E_ * (MPE / 128) * (D_ / 128);  // 640 GEMM2 blocks

  prep_kernel<<<twiT + BS_ / 4, 256, 0, stream>>>(
      hs, rw, wi, wiT, logits, maxp, eidx, twiT);
  scan_kernel<<<B_ * E_, 256, 0, stream>>>(eidx, tok, eout, hs, maxp, out);
  gather_kernel<<<E_ * MPE, 256, 0, stream>>>(hs, tok, Xg);

  if (big) {
    moe_g<1><<<g1 + twoT, 256, 0, stream>>>(
        Xg, wiT, hg, nullptr, tok, maxp, D_, F_ / 128, g1, wo, woT);
  } else {
    moe_g<1><<<g1, 256, 0, stream>>>(
        Xg, wiT, hg, nullptr, tok, maxp, D_, F_ / 128, g1, nullptr, nullptr);
    transpose_kernel<<<twoT, 256, 0, stream>>>(wo, woT, F_, D_);
  }
  moe_g<2><<<g2, 256, 0, stream>>>(
      hg, woT, nullptr, out, tok, maxp, F_, D_ / 128, g2, nullptr, nullptr);
}

// Round 10
// 359.693 us; speedup vs baseline: 1.0740x; 1.0740x over previous
//
#include <hip/hip_runtime.h>
#include <hip/hip_bf16.h>
#include <stdint.h>

#define B_ 4
#define S_ 2048
#define D_ 1024
#define F_ 4096
#define E_ 8
#define CAP_ 320
#define BS_ (B_*S_)      // 8192 tokens
#define MPE 1280         // B_*CAP_ rows per expert

typedef unsigned short u16;
typedef __attribute__((ext_vector_type(8))) short bf16x8;
typedef __attribute__((ext_vector_type(4))) float f32x4;
typedef __attribute__((ext_vector_type(4))) unsigned short u16x4;
typedef __attribute__((ext_vector_type(8))) unsigned short u16x8;

__device__ __forceinline__ u16 f2bf(float f) {
  union { float f; uint32_t u; } v; v.f = f;
  uint32_t r = (v.u + 0x7FFFu + ((v.u >> 16) & 1u)) >> 16;
  return (u16)r;
}

__device__ __forceinline__ void gload16(const void* g, void* l) {
  __builtin_amdgcn_global_load_lds(
      (const __attribute__((address_space(1))) uint32_t*)g,
      (__attribute__((address_space(3))) uint32_t*)l, 16, 0, 0);
}

// ---------------------------------------------------------------------------
// Transpose+convert block (512 threads): W[e][K][N] f32 -> WT[e][N][K] bf16.
// Tile = 128 K-rows x 64 N-cols.
// ---------------------------------------------------------------------------
__device__ __forceinline__ void transpose_block(
    const float* __restrict__ W, u16* __restrict__ WT,
    const int K, const int N, const int bid, void* ldsraw)
{
  float (*tile)[65] = (float(*)[65])ldsraw;
  const int tk = K >> 7, tn = N >> 6;
  const int e = bid / (tk * tn), r = bid % (tk * tn);
  const int k0 = (r / tn) << 7, n0 = (r % tn) << 6;
  const float* We = W + (size_t)e * K * N;
  u16* WTe = WT + (size_t)e * N * K;
  const int t = threadIdx.x;
  const int fr = t >> 2, c0 = (t & 3) * 16;
#pragma unroll
  for (int j = 0; j < 4; ++j) {
    const float4 v = *(const float4*)(We + (size_t)(k0 + fr) * N + n0 + c0 + j * 4);
    tile[fr][c0 + j*4 + 0] = v.x; tile[fr][c0 + j*4 + 1] = v.y;
    tile[fr][c0 + j*4 + 2] = v.z; tile[fr][c0 + j*4 + 3] = v.w;
  }
  __syncthreads();
  const int nr = t >> 3, kk0 = (t & 7) * 16;
  u16x8 o0, o1;
#pragma unroll
  for (int j = 0; j < 8; ++j) o0[j] = f2bf(tile[kk0 + j][nr]);
#pragma unroll
  for (int j = 0; j < 8; ++j) o1[j] = f2bf(tile[kk0 + 8 + j][nr]);
  u16* dst = WTe + (size_t)(n0 + nr) * K + k0 + kk0;
  *(u16x8*)dst = o0;
  *(u16x8*)(dst + 8) = o1;
}

__global__ __launch_bounds__(512) void transpose_kernel(
    const float* __restrict__ W, u16* __restrict__ WT, const int K, const int N)
{
  __shared__ __align__(16) float tile[128][65];
  transpose_block(W, WT, K, N, blockIdx.x, (void*)tile);
}

// ---------------------------------------------------------------------------
// Prep: blocks [0,twiT) = wi transpose; rest = router (8 tokens/block).
// ---------------------------------------------------------------------------
__global__ __launch_bounds__(512) void prep_kernel(
    const float* __restrict__ hs, const float* __restrict__ rw,
    const float* __restrict__ wi, u16* __restrict__ wT,
    float* __restrict__ logits, float* __restrict__ maxp,
    int* __restrict__ eidx, const int twiT)
{
  __shared__ __align__(16) float tile[128][65];
  if ((int)blockIdx.x < twiT) {
    transpose_block(wi, wT, D_, F_, blockIdx.x, (void*)tile);
    return;
  }
  const int wv = threadIdx.x >> 6, l = threadIdx.x & 63;
  const int token = (blockIdx.x - twiT) * 8 + wv;
  const float* row = hs + (size_t)token * D_;
  const float4* rw4 = (const float4*)rw;

  double acc0=0, acc1=0, acc2=0, acc3=0, acc4=0, acc5=0, acc6=0, acc7=0;
#pragma unroll
  for (int j = 0; j < 4; ++j) {
    const int d4 = l + j * 64;
    const float4 v = ((const float4*)row)[d4];
#pragma unroll
    for (int c = 0; c < 4; ++c) {
      const int d = d4 * 4 + c;
      const float x = (&v.x)[c];
      const float4 w0 = rw4[d * 2];
      const float4 w1 = rw4[d * 2 + 1];
      acc0 += (double)x * (double)w0.x;
      acc1 += (double)x * (double)w0.y;
      acc2 += (double)x * (double)w0.z;
      acc3 += (double)x * (double)w0.w;
      acc4 += (double)x * (double)w1.x;
      acc5 += (double)x * (double)w1.y;
      acc6 += (double)x * (double)w1.z;
      acc7 += (double)x * (double)w1.w;
    }
  }
  double acc[E_] = {acc0, acc1, acc2, acc3, acc4, acc5, acc6, acc7};
#pragma unroll
  for (int e = 0; e < E_; ++e) {
#pragma unroll
    for (int off = 32; off; off >>= 1)
      acc[e] += __shfl_xor(acc[e], off);
  }
  if (l == 0) {
    float lg[E_];
#pragma unroll
    for (int e = 0; e < E_; ++e) lg[e] = (float)acc[e];
    float lmax = lg[0]; int am = 0;
#pragma unroll
    for (int e = 1; e < E_; ++e) { if (lg[e] > lmax) { lmax = lg[e]; am = e; } }
    float sum = 0.f;
#pragma unroll
    for (int e = 0; e < E_; ++e) sum += expf(lg[e] - lmax);
#pragma unroll
    for (int e = 0; e < E_; ++e) logits[(size_t)token * E_ + e] = lg[e];
    maxp[token] = 1.0f / sum;
    eidx[token] = am;
  }
}

// ---------------------------------------------------------------------------
// Capacity scan: one block per (b,e). Also: tok init (-1), eout, and
// out rows for DROPPED tokens (out = maxp * hs).
// ---------------------------------------------------------------------------
__global__ __launch_bounds__(256) void scan_kernel(
    const int* __restrict__ eidx, int* __restrict__ tok,
    float* __restrict__ eout, const float* __restrict__ hs,
    const float* __restrict__ maxp, float* __restrict__ out)
{
  const int b = blockIdx.x >> 3, e = blockIdx.x & 7;
  __shared__ int wsum[4];
  const int tid = threadIdx.x, wv = tid >> 6, l = tid & 63;
  for (int i = tid; i < CAP_; i += 256) tok[(b * E_ + e) * CAP_ + i] = -1;
  __syncthreads();
  int base = 0;
  for (int ch = 0; ch < S_ / 256; ++ch) {
    const int s = ch * 256 + tid;
    const bool p = (eidx[b * S_ + s] == e);
    const unsigned long long m = __ballot(p);
    const int lp = __popcll(m & ((1ULL << l) - 1ULL));
    if (l == 0) wsum[wv] = __popcll(m);
    __syncthreads();
    int pre = 0, tot = 0;
#pragma unroll
    for (int w = 0; w < 4; ++w) { if (w < wv) pre += wsum[w]; tot += wsum[w]; }
    if (p) {
      const int rank = base + pre + lp;
      if (rank < CAP_) {
        tok[(b * E_ + e) * CAP_ + rank] = s;
        eout[b * S_ + s] = (float)e;
      } else {
        eout[b * S_ + s] = 0.0f;
        const float mp = maxp[b * S_ + s];
        const float4* src = (const float4*)(hs + (size_t)(b * S_ + s) * D_);
        float4* dst = (float4*)(out + (size_t)(b * S_ + s) * D_);
        for (int j = 0; j < D_ / 4; ++j) {
          const float4 vv = src[j];
          float4 o; o.x = vv.x * mp; o.y = vv.y * mp; o.z = vv.z * mp; o.w = vv.w * mp;
          dst[j] = o;
        }
      }
    }
    base += tot;
    __syncthreads();
  }
}

// ---------------------------------------------------------------------------
// Gather routed tokens -> Xg[e][b*CAP+c][D] bf16 (zeros for empty slots)
// ---------------------------------------------------------------------------
__global__ __launch_bounds__(256) void gather_kernel(
    const float* __restrict__ hs, const int* __restrict__ tok,
    u16* __restrict__ Xg)
{
  const int bx = blockIdx.x;
  const int e = bx / MPE, r = bx % MPE;
  const int b = r / CAP_, c = r % CAP_;
  const int t = tok[(b * E_ + e) * CAP_ + c];
  const int d = threadIdx.x * 4;
  u16x4 o;
  if (t >= 0) {
    const float4 vv = *(const float4*)(hs + ((size_t)(b * S_ + t)) * D_ + d);
    o[0] = f2bf(vv.x); o[1] = f2bf(vv.y); o[2] = f2bf(vv.z); o[3] = f2bf(vv.w);
  } else {
    o[0] = 0; o[1] = 0; o[2] = 0; o[3] = 0;
  }
  *(u16x4*)(Xg + (size_t)bx * D_ + d) = o;
}

// ---------------------------------------------------------------------------
// Shared GEMM helper macros
// ---------------------------------------------------------------------------
#define BAR() __builtin_amdgcn_s_barrier()
#define LGKMN(n) do { asm volatile("s_waitcnt lgkmcnt(" #n ")" ::: "memory"); \
                      __builtin_amdgcn_sched_barrier(0); } while (0)
#define VMW(n) asm volatile("s_waitcnt vmcnt(" #n ")" ::: "memory")

// ---------------------------------------------------------------------------
// GEMM1 (r8-proven): hg = relu(Xg @ wiT^T). Tile 128x256, BK=64, 8 waves,
// 96 KiB LDS, grid 1280 (+ fused wo-transpose into DISJOINT woT).
// ---------------------------------------------------------------------------
__global__ __launch_bounds__(512, 2) void moe_g1(
    const u16* __restrict__ Aall, const u16* __restrict__ Btall,
    u16* __restrict__ hgout, const int gemm_blocks,
    const float* __restrict__ Wtr, u16* __restrict__ WTtr)
{
  __shared__ __align__(16) u16 lds[49152];   // 96 KiB

#define LDA(p, h) (lds + (p) * 8192 + (h) * 4096)
#define LDB(p, h) (lds + 16384 + (p) * 16384 + (h) * 8192)

  if ((int)blockIdx.x >= gemm_blocks) {
    transpose_block(Wtr, WTtr, F_, D_, blockIdx.x - gemm_blocks, (void*)lds);
    return;
  }
  const int K = D_, NT = K >> 6, N = F_;
  const int cpx = gemm_blocks >> 3;
  const int bid = blockIdx.x;
  const int swzb = (bid & 7) * cpx + (bid >> 3);
  const int e = swzb / 160, rem = swzb % 160;
  const int m0 = (rem / 16) * 128, n0 = (rem % 16) * 256;

  const u16* Ae = Aall + (size_t)e * MPE * K;
  const u16* Be = Btall + (size_t)e * N * K;

  const int tid = threadIdx.x;
  const int wv = tid >> 6, l = tid & 63;
  const int wr = wv >> 2, wc = wv & 3;
  const int lr = l & 15, lk = l >> 4;
  const int rswz = ((lr >> 3) & 1) << 4;
  const int gs0 = tid ^ (((tid >> 5) & 1) << 1);
  const size_t goffB = (size_t)((gs0 >> 2) & 127) * K + (size_t)((gs0 & 3) * 8);
  const size_t goffA = (size_t)((gs0 >> 2) & 63) * K
                     + (size_t)(((gs0 >> 8) & 1) * 32) + (size_t)((gs0 & 3) * 8);
  const int dwoff = wv * 512;

  const u16* pA0 = Ae + (size_t)m0 * K;
  const u16* pA1 = Ae + (size_t)(m0 + 64) * K;
  const u16* pB0 = Be + (size_t)n0 * K;
  const u16* pB1 = Be + (size_t)(n0 + 128) * K;

  f32x4 acc[4][4];
#pragma unroll
  for (int i = 0; i < 4; ++i)
#pragma unroll
    for (int j = 0; j < 4; ++j) acc[i][j] = (f32x4){0.f, 0.f, 0.f, 0.f};

  bf16x8 faA[2], faB[2], fb[8];

#define STAGE_A1(dhalf, rb, tt) \
    gload16((rb) + goffA + (size_t)((tt) * 64), (dhalf) + dwoff)

#define STAGE_B1(dhalf, rb, tt) do {                                       \
    const u16* s_ = (rb) + goffB + (size_t)((tt) * 64);                    \
    gload16(s_,      (dhalf) + dwoff);                                     \
    gload16(s_ + 32, (dhalf) + 4096 + dwoff);                              \
  } while (0)

#define READ_AQ1(q, p, fa_) do {                                           \
    _Pragma("unroll")                                                      \
    for (int kk = 0; kk < 2; ++kk)                                         \
      fa_[kk] = *(const bf16x8*)&LDA(p, wr)                                \
          [(kk*64 + (q)*16 + lr)*32 + ((lk*8) ^ rswz)];                    \
  } while (0)

#define READ_B_ALL1(p) do {                                                \
    _Pragma("unroll")                                                      \
    for (int nf = 0; nf < 4; ++nf)                                         \
      _Pragma("unroll")                                                    \
      for (int kk = 0; kk < 2; ++kk)                                       \
        fb[nf*2+kk] = *(const bf16x8*)&LDB(p, wc>>1)                       \
            [(kk*128 + (wc&1)*64 + (nf>>1)*32 + (nf&1)*16 + lr)*32         \
             + ((lk*8) ^ rswz)];                                           \
  } while (0)

#define MFMA_P1(q, fa_) do {                                               \
    __builtin_amdgcn_s_setprio(1);                                         \
    _Pragma("unroll")                                                      \
    for (int nf = 0; nf < 4; ++nf)                                         \
      _Pragma("unroll")                                                    \
      for (int kk = 0; kk < 2; ++kk)                                       \
        acc[q][nf] = __builtin_amdgcn_mfma_f32_16x16x32_bf16(              \
            fa_[kk], fb[nf*2+kk], acc[q][nf], 0, 0, 0);                    \
    __builtin_amdgcn_s_setprio(0);                                         \
  } while (0)

#define DO_T1(p, pn, tc) do {                                              \
    READ_AQ1(1, p, faB);                                                   \
    if ((tc) + 1 < NT) { STAGE_A1(LDA(pn,0), pA0, (tc)+1);                 \
                         STAGE_A1(LDA(pn,1), pA1, (tc)+1); }               \
    LGKMN(2); MFMA_P1(0, faA);                                             \
    READ_AQ1(2, p, faA);                                                   \
    LGKMN(2); MFMA_P1(1, faB);                                             \
    BAR();                                                                 \
    READ_AQ1(3, p, faB);                                                   \
    if ((tc) + 2 < NT) { STAGE_B1(LDB(p,0), pB0, (tc)+2);                  \
                         STAGE_B1(LDB(p,1), pB1, (tc)+2); }                \
    LGKMN(2); MFMA_P1(2, faA);                                             \
    LGKMN(0); MFMA_P1(3, faB);                                             \
    if ((tc) >= NT - 2) VMW(0); else VMW(4);                               \
    BAR();                                                                 \
    if ((tc) + 1 < NT) { READ_B_ALL1(pn); READ_AQ1(0, pn, faA); }          \
  } while (0)

  STAGE_A1(LDA(0,0), pA0, 0);
  STAGE_A1(LDA(0,1), pA1, 0);
  STAGE_B1(LDB(0,0), pB0, 0);
  STAGE_B1(LDB(0,1), pB1, 0);
  STAGE_B1(LDB(1,0), pB0, 1);
  STAGE_B1(LDB(1,1), pB1, 1);
  VMW(4); BAR();
  READ_B_ALL1(0); READ_AQ1(0, 0, faA);

  for (int t = 0; t < NT; t += 2) {
    DO_T1(0, 1, t);
    DO_T1(1, 0, t + 1);
  }

#pragma unroll
  for (int i = 0; i < 4; ++i) {
#pragma unroll
    for (int r = 0; r < 4; ++r) {
      const int grow = m0 + wr * 64 + i * 16 + lk * 4 + r;
      u16* hrow = hgout + ((size_t)e * MPE + grow) * (size_t)N + n0 + wc * 64;
#pragma unroll
      for (int j = 0; j < 4; ++j)
        hrow[j * 16 + lr] = f2bf(fmaxf(acc[i][j][r], 0.0f));
    }
  }
#undef LDA
#undef LDB
#undef STAGE_A1
#undef STAGE_B1
#undef READ_AQ1
#undef READ_B_ALL1
#undef MFMA_P1
#undef DO_T1
}

// ---------------------------------------------------------------------------
// GEMM2: out = maxp * (hg @ woT^T) scattered. Tile 320x128, BK=64, 8 waves
// (2Mx4N -> per-wave 160x32, acc[10][2]), 112 KiB LDS, grid 256 = EXACT one
// round on 256 CUs. Read-ahead schedule: A in 5 chunks (dbuf fa), B once/tile;
// LGKMN(4) between chunks; stage A(t+1) early [5 gloads], B(t+2) mid [2];
// VMW(2) at tile end (A(t+1) drained, B(t+2) in flight). m-tile = one batch.
// ---------------------------------------------------------------------------
__global__ __launch_bounds__(512, 1) void moe_g2(
    const u16* __restrict__ Aall, const u16* __restrict__ Btall,
    float* __restrict__ out, const int* __restrict__ tok,
    const float* __restrict__ maxp)
{
  __shared__ __align__(16) u16 ldsA[2][20480];   // [buf][kk*10240+row*32+e] 80 KiB
  __shared__ __align__(16) u16 ldsB[2][8192];    // [buf][kk*4096+row*32+e]  32 KiB

  const int K = F_, NT = K >> 6;
  const int bid = blockIdx.x;
  const int swzb = (bid & 7) * 32 + (bid >> 3);  // grid 256, cpx=32
  const int e = swzb >> 5, rem = swzb & 31;
  const int m0 = (rem >> 3) * 320, n0 = (rem & 7) * 128;
  const int b = m0 / CAP_;                        // block-uniform batch

  const u16* pA = Aall + (size_t)e * MPE * K + (size_t)m0 * K;
  const u16* pB = Btall + (size_t)e * D_ * K + (size_t)n0 * K;

  const int tid = threadIdx.x;
  const int wv = tid >> 6, l = tid & 63;
  const int wr = wv >> 2, wc = wv & 3;
  const int lr = l & 15, lk = l >> 4;
  const int rswz = ((lr >> 3) & 1) << 4;
  const int gs0 = tid ^ (((tid >> 5) & 1) << 1);
  const size_t goff = (size_t)((gs0 >> 2) & 127) * K + (size_t)((gs0 & 3) * 8);
  const size_t goffR = (size_t)(256 + ((gs0 >> 2) & 63)) * K + (size_t)((gs0 & 3) * 8);
  const int dwoff = wv * 512;
  const int dwoff4 = (wv & 3) * 512;
  const size_t r128K = (size_t)128 * K;

  f32x4 acc[10][2];
#pragma unroll
  for (int i = 0; i < 10; ++i)
#pragma unroll
    for (int j = 0; j < 2; ++j) acc[i][j] = (f32x4){0.f, 0.f, 0.f, 0.f};

  bf16x8 faA[4], faB[4], fb[4];

  // A tile = 320 rows: 4 full 128-row units + 1 wave-split 64-row remainder
  // (uniform 5 vm-instructions per wave).
#define STAGE_A2(p, tt) do {                                               \
    const u16* s_ = pA + goff + (size_t)((tt) * 64);                       \
    gload16(s_,             &ldsA[p][0]     + dwoff);                      \
    gload16(s_ + r128K,     &ldsA[p][4096]  + dwoff);                      \
    gload16(s_ + 32,        &ldsA[p][10240] + dwoff);                      \
    gload16(s_ + r128K + 32,&ldsA[p][14336] + dwoff);                      \
    const u16* sR = pA + goffR + (size_t)((tt) * 64);                      \
    if (wv < 4) gload16(sR,      &ldsA[p][8192]  + dwoff4);                \
    else        gload16(sR + 32, &ldsA[p][18432] + dwoff4);                \
  } while (0)

#define STAGE_B2(p, tt) do {                                               \
    const u16* s_ = pB + goff + (size_t)((tt) * 64);                       \
    gload16(s_,      &ldsB[p][0]    + dwoff);                              \
    gload16(s_ + 32, &ldsB[p][4096] + dwoff);                              \
  } while (0)

  // chunk q: m-frags 2q, 2q+1 (rows wr*160 + (2q+mf)*16 + lr), kk 0..1
#define READ_CH2(q, p, fa_) do {                                           \
    _Pragma("unroll")                                                      \
    for (int mf = 0; mf < 2; ++mf)                                         \
      _Pragma("unroll")                                                    \
      for (int kk = 0; kk < 2; ++kk)                                       \
        fa_[mf*2+kk] = *(const bf16x8*)&ldsA[p]                            \
            [(kk*320 + wr*160 + ((q)*2+mf)*16 + lr)*32 + ((lk*8) ^ rswz)]; \
  } while (0)

#define READ_B_ALL2(p) do {                                                \
    _Pragma("unroll")                                                      \
    for (int nf = 0; nf < 2; ++nf)                                         \
      _Pragma("unroll")                                                    \
      for (int kk = 0; kk < 2; ++kk)                                       \
        fb[nf*2+kk] = *(const bf16x8*)&ldsB[p]                             \
            [(kk*128 + wc*32 + nf*16 + lr)*32 + ((lk*8) ^ rswz)];          \
  } while (0)

#define MFMA_CH2(q, fa_) do {                                              \
    __builtin_amdgcn_s_setprio(1);                                         \
    _Pragma("unroll")                                                      \
    for (int mf = 0; mf < 2; ++mf)                                         \
      _Pragma("unroll")                                                    \
      for (int nf = 0; nf < 2; ++nf)                                       \
        _Pragma("unroll")                                                  \
        for (int kk = 0; kk < 2; ++kk)                                     \
          acc[(q)*2+mf][nf] = __builtin_amdgcn_mfma_f32_16x16x32_bf16(     \
              fa_[mf*2+kk], fb[nf*2+kk], acc[(q)*2+mf][nf], 0, 0, 0);      \
    __builtin_amdgcn_s_setprio(0);                                         \
  } while (0)

  // fE holds chunk0 at tile start; reads alternate fO/fE; next tile c0 -> fO.
#define DO_T2(p, pn, tc, fE, fO) do {                                      \
    READ_CH2(1, p, fO);                                                    \
    if ((tc) + 1 < NT) STAGE_A2(pn, (tc) + 1);                             \
    LGKMN(4); MFMA_CH2(0, fE);                                             \
    READ_CH2(2, p, fE);                                                    \
    LGKMN(4); MFMA_CH2(1, fO);                                             \
    BAR();                                                                 \
    READ_CH2(3, p, fO);                                                    \
    if ((tc) + 2 < NT) STAGE_B2(p, (tc) + 2);                              \
    LGKMN(4); MFMA_CH2(2, fE);                                             \
    READ_CH2(4, p, fE);                                                    \
    LGKMN(4); MFMA_CH2(3, fO);                                             \
    LGKMN(0); MFMA_CH2(4, fE);                                             \
    if ((tc) >= NT - 2) VMW(0); else VMW(2);                               \
    BAR();                                                                 \
    if ((tc) + 1 < NT) { READ_B_ALL2(pn); READ_CH2(0, pn, fO); }           \
  } while (0)

  // Prologue: A(0)[5], B(0)[2], B(1)[2]; VMW(2) drains A(0)+B(0).
  STAGE_A2(0, 0);
  STAGE_B2(0, 0);
  STAGE_B2(1, 1);
  VMW(2); BAR();
  READ_B_ALL2(0); READ_CH2(0, 0, faA);

  for (int t = 0; t < NT; t += 2) {
    DO_T2(0, 1, t,     faA, faB);
    DO_T2(1, 0, t + 1, faB, faA);
  }

  // Epilogue: rows c = wr*160 + i*16 + lk*4 + r (CAP slot, batch b uniform);
  // cols n0 + wc*32 + nf*16 + lr.
#pragma unroll
  for (int i = 0; i < 10; ++i) {
#pragma unroll
    for (int r = 0; r < 4; ++r) {
      const int c = wr * 160 + i * 16 + lk * 4 + r;
      const int t = tok[(b * E_ + e) * CAP_ + c];
      if (t >= 0) {
        const float sc = maxp[b * S_ + t];
        float* orow = out + ((size_t)(b * S_ + t)) * D_ + n0 + wc * 32;
        orow[lr]      = sc * acc[i][0][r];
        orow[16 + lr] = sc * acc[i][1][r];
      }
    }
  }
#undef STAGE_A2
#undef STAGE_B2
#undef READ_CH2
#undef READ_B_ALL2
#undef MFMA_CH2
#undef DO_T2
}

// ---------------------------------------------------------------------------
extern "C" void kernel_launch(void* const* d_in, const int* in_sizes, int n_in,
                              void* d_out, int out_size, void* d_ws, size_t ws_size,
                              hipStream_t stream)
{
  const float* hs = (const float*)d_in[0];
  const float* rw = (const float*)d_in[1];
  const float* wi = (const float*)d_in[2];
  const float* wo = (const float*)d_in[3];

  float* out    = (float*)d_out;
  float* logits = out + (size_t)BS_ * D_;
  float* eout   = logits + (size_t)BS_ * E_;

  uint8_t* ws = (uint8_t*)d_ws;
  int*   tok  = (int*)(ws + 0);                 //   40,960 B
  float* maxp = (float*)(ws + 40960);           //   32,768 B
  int*   eidx = (int*)(ws + 73728);             //   32,768 B
  u16*   Xg   = (u16*)(ws + 131072);            // 20,971,520 B
  u16*   hg   = (u16*)(ws + 21102592);          // 83,886,080 B
  u16*   wiT  = (u16*)(ws + 104988672);         // 67,108,864 B
  if (ws_size < 172097536ULL) return;
  const bool big = ws_size >= 239206400ULL;
  u16* woT = big ? (u16*)(ws + 172097536) : wiT;

  const int twiT = E_ * (D_ / 128) * (F_ / 64);  // 4096 wi-transpose blocks
  const int twoT = E_ * (F_ / 128) * (D_ / 64);  // 4096 wo-transpose blocks
  const int g1 = E_ * (MPE / 128) * (F_ / 256);  // 1280 GEMM1 blocks (5 rounds)
  const int g2 = 256;                            // GEMM2: exact one round

  prep_kernel<<<twiT + BS_ / 8, 512, 0, stream>>>(
      hs, rw, wi, wiT, logits, maxp, eidx, twiT);
  scan_kernel<<<B_ * E_, 256, 0, stream>>>(eidx, tok, eout, hs, maxp, out);
  gather_kernel<<<E_ * MPE, 256, 0, stream>>>(hs, tok, Xg);

  if (big) {
    moe_g1<<<g1 + twoT, 512, 0, stream>>>(Xg, wiT, hg, g1, wo, woT);
  } else {
    moe_g1<<<g1, 512, 0, stream>>>(Xg, wiT, hg, g1, nullptr, nullptr);
    transpose_kernel<<<twoT, 512, 0, stream>>>(wo, woT, F_, D_);
  }
  moe_g2<<<g2, 512, 0, stream>>>(hg, woT, out, tok, maxp);
}

// Round 11
// 326.871 us; speedup vs baseline: 1.1819x; 1.1004x over previous
//
#include <hip/hip_runtime.h>
#include <hip/hip_bf16.h>
#include <stdint.h>

#define B_ 4
#define S_ 2048
#define D_ 1024
#define F_ 4096
#define E_ 8
#define CAP_ 320
#define BS_ (B_*S_)      // 8192 tokens
#define MPE 1280         // B_*CAP_ rows per expert

typedef unsigned short u16;
typedef __attribute__((ext_vector_type(8))) short bf16x8;
typedef __attribute__((ext_vector_type(4))) float f32x4;
typedef __attribute__((ext_vector_type(4))) unsigned short u16x4;
typedef __attribute__((ext_vector_type(8))) unsigned short u16x8;

__device__ __forceinline__ u16 f2bf(float f) {
  union { float f; uint32_t u; } v; v.f = f;
  uint32_t r = (v.u + 0x7FFFu + ((v.u >> 16) & 1u)) >> 16;
  return (u16)r;
}

__device__ __forceinline__ void gload16(const void* g, void* l) {
  __builtin_amdgcn_global_load_lds(
      (const __attribute__((address_space(1))) uint32_t*)g,
      (__attribute__((address_space(3))) uint32_t*)l, 16, 0, 0);
}

// ---------------------------------------------------------------------------
// Transpose+convert block (512 threads): W[e][K][N] f32 -> WT[e][N][K] bf16.
// Tile = 128 K-rows x 64 N-cols.
// ---------------------------------------------------------------------------
__device__ __forceinline__ void transpose_block(
    const float* __restrict__ W, u16* __restrict__ WT,
    const int K, const int N, const int bid, void* ldsraw)
{
  float (*tile)[65] = (float(*)[65])ldsraw;
  const int tk = K >> 7, tn = N >> 6;
  const int e = bid / (tk * tn), r = bid % (tk * tn);
  const int k0 = (r / tn) << 7, n0 = (r % tn) << 6;
  const float* We = W + (size_t)e * K * N;
  u16* WTe = WT + (size_t)e * N * K;
  const int t = threadIdx.x;
  const int fr = t >> 2, c0 = (t & 3) * 16;
#pragma unroll
  for (int j = 0; j < 4; ++j) {
    const float4 v = *(const float4*)(We + (size_t)(k0 + fr) * N + n0 + c0 + j * 4);
    tile[fr][c0 + j*4 + 0] = v.x; tile[fr][c0 + j*4 + 1] = v.y;
    tile[fr][c0 + j*4 + 2] = v.z; tile[fr][c0 + j*4 + 3] = v.w;
  }
  __syncthreads();
  const int nr = t >> 3, kk0 = (t & 7) * 16;
  u16x8 o0, o1;
#pragma unroll
  for (int j = 0; j < 8; ++j) o0[j] = f2bf(tile[kk0 + j][nr]);
#pragma unroll
  for (int j = 0; j < 8; ++j) o1[j] = f2bf(tile[kk0 + 8 + j][nr]);
  u16* dst = WTe + (size_t)(n0 + nr) * K + k0 + kk0;
  *(u16x8*)dst = o0;
  *(u16x8*)(dst + 8) = o1;
}

__global__ __launch_bounds__(512) void transpose_kernel(
    const float* __restrict__ W, u16* __restrict__ WT, const int K, const int N)
{
  __shared__ __align__(16) float tile[128][65];
  transpose_block(W, WT, K, N, blockIdx.x, (void*)tile);
}

// ---------------------------------------------------------------------------
// Prep: blocks [0,twiT) = wi transpose; rest = router (8 tokens/block).
// ---------------------------------------------------------------------------
__global__ __launch_bounds__(512) void prep_kernel(
    const float* __restrict__ hs, const float* __restrict__ rw,
    const float* __restrict__ wi, u16* __restrict__ wT,
    float* __restrict__ logits, float* __restrict__ maxp,
    int* __restrict__ eidx, const int twiT)
{
  __shared__ __align__(16) float tile[128][65];
  if ((int)blockIdx.x < twiT) {
    transpose_block(wi, wT, D_, F_, blockIdx.x, (void*)tile);
    return;
  }
  const int wv = threadIdx.x >> 6, l = threadIdx.x & 63;
  const int token = (blockIdx.x - twiT) * 8 + wv;
  const float* row = hs + (size_t)token * D_;
  const float4* rw4 = (const float4*)rw;

  double acc0=0, acc1=0, acc2=0, acc3=0, acc4=0, acc5=0, acc6=0, acc7=0;
#pragma unroll
  for (int j = 0; j < 4; ++j) {
    const int d4 = l + j * 64;
    const float4 v = ((const float4*)row)[d4];
#pragma unroll
    for (int c = 0; c < 4; ++c) {
      const int d = d4 * 4 + c;
      const float x = (&v.x)[c];
      const float4 w0 = rw4[d * 2];
      const float4 w1 = rw4[d * 2 + 1];
      acc0 += (double)x * (double)w0.x;
      acc1 += (double)x * (double)w0.y;
      acc2 += (double)x * (double)w0.z;
      acc3 += (double)x * (double)w0.w;
      acc4 += (double)x * (double)w1.x;
      acc5 += (double)x * (double)w1.y;
      acc6 += (double)x * (double)w1.z;
      acc7 += (double)x * (double)w1.w;
    }
  }
  double acc[E_] = {acc0, acc1, acc2, acc3, acc4, acc5, acc6, acc7};
#pragma unroll
  for (int e = 0; e < E_; ++e) {
#pragma unroll
    for (int off = 32; off; off >>= 1)
      acc[e] += __shfl_xor(acc[e], off);
  }
  if (l == 0) {
    float lg[E_];
#pragma unroll
    for (int e = 0; e < E_; ++e) lg[e] = (float)acc[e];
    float lmax = lg[0]; int am = 0;
#pragma unroll
    for (int e = 1; e < E_; ++e) { if (lg[e] > lmax) { lmax = lg[e]; am = e; } }
    float sum = 0.f;
#pragma unroll
    for (int e = 0; e < E_; ++e) sum += expf(lg[e] - lmax);
#pragma unroll
    for (int e = 0; e < E_; ++e) logits[(size_t)token * E_ + e] = lg[e];
    maxp[token] = 1.0f / sum;
    eidx[token] = am;
  }
}

// ---------------------------------------------------------------------------
// Capacity scan: one block per (b,e). Also: tok init (-1), eout, and
// out rows for DROPPED tokens (out = maxp * hs).
// ---------------------------------------------------------------------------
__global__ __launch_bounds__(256) void scan_kernel(
    const int* __restrict__ eidx, int* __restrict__ tok,
    float* __restrict__ eout, const float* __restrict__ hs,
    const float* __restrict__ maxp, float* __restrict__ out)
{
  const int b = blockIdx.x >> 3, e = blockIdx.x & 7;
  __shared__ int wsum[4];
  const int tid = threadIdx.x, wv = tid >> 6, l = tid & 63;
  for (int i = tid; i < CAP_; i += 256) tok[(b * E_ + e) * CAP_ + i] = -1;
  __syncthreads();
  int base = 0;
  for (int ch = 0; ch < S_ / 256; ++ch) {
    const int s = ch * 256 + tid;
    const bool p = (eidx[b * S_ + s] == e);
    const unsigned long long m = __ballot(p);
    const int lp = __popcll(m & ((1ULL << l) - 1ULL));
    if (l == 0) wsum[wv] = __popcll(m);
    __syncthreads();
    int pre = 0, tot = 0;
#pragma unroll
    for (int w = 0; w < 4; ++w) { if (w < wv) pre += wsum[w]; tot += wsum[w]; }
    if (p) {
      const int rank = base + pre + lp;
      if (rank < CAP_) {
        tok[(b * E_ + e) * CAP_ + rank] = s;
        eout[b * S_ + s] = (float)e;
      } else {
        eout[b * S_ + s] = 0.0f;
        const float mp = maxp[b * S_ + s];
        const float4* src = (const float4*)(hs + (size_t)(b * S_ + s) * D_);
        float4* dst = (float4*)(out + (size_t)(b * S_ + s) * D_);
        for (int j = 0; j < D_ / 4; ++j) {
          const float4 vv = src[j];
          float4 o; o.x = vv.x * mp; o.y = vv.y * mp; o.z = vv.z * mp; o.w = vv.w * mp;
          dst[j] = o;
        }
      }
    }
    base += tot;
    __syncthreads();
  }
}

// ---------------------------------------------------------------------------
// Gather routed tokens -> Xg[e][b*CAP+c][D] bf16 (zeros for empty slots)
// ---------------------------------------------------------------------------
__global__ __launch_bounds__(256) void gather_kernel(
    const float* __restrict__ hs, const int* __restrict__ tok,
    u16* __restrict__ Xg)
{
  const int bx = blockIdx.x;
  const int e = bx / MPE, r = bx % MPE;
  const int b = r / CAP_, c = r % CAP_;
  const int t = tok[(b * E_ + e) * CAP_ + c];
  const int d = threadIdx.x * 4;
  u16x4 o;
  if (t >= 0) {
    const float4 vv = *(const float4*)(hs + ((size_t)(b * S_ + t)) * D_ + d);
    o[0] = f2bf(vv.x); o[1] = f2bf(vv.y); o[2] = f2bf(vv.z); o[3] = f2bf(vv.w);
  } else {
    o[0] = 0; o[1] = 0; o[2] = 0; o[3] = 0;
  }
  *(u16x4*)(Xg + (size_t)bx * D_ + d) = o;
}

// ---------------------------------------------------------------------------
// Shared GEMM helper macros
// ---------------------------------------------------------------------------
#define BAR() __builtin_amdgcn_s_barrier()
#define LGKMN(n) do { asm volatile("s_waitcnt lgkmcnt(" #n ")" ::: "memory"); \
                      __builtin_amdgcn_sched_barrier(0); } while (0)
#define VMW(n) asm volatile("s_waitcnt vmcnt(" #n ")" ::: "memory")

// ---------------------------------------------------------------------------
// GEMM1: hg = relu(Xg @ wiT^T). Tile 128x256, BK=64, 8 waves (2Mx4N),
// 96 KiB LDS, grid 1280 (+ fused wo-transpose into DISJOINT woT).
// Read-ahead pipelined K-tile (r8-proven). Block order n-major within expert:
// 10 consecutive same-XCD blocks share one 0.5MB B panel (L2-hot) and stream
// 2.5MB of A panels (also L2-fit) -> wiT fetched ~once from HBM.
// ---------------------------------------------------------------------------
__global__ __launch_bounds__(512, 2) void moe_g1(
    const u16* __restrict__ Aall, const u16* __restrict__ Btall,
    u16* __restrict__ hgout, const int gemm_blocks,
    const float* __restrict__ Wtr, u16* __restrict__ WTtr)
{
  __shared__ __align__(16) u16 lds[49152];   // 96 KiB

#define LDA(p, h) (lds + (p) * 8192 + (h) * 4096)
#define LDB(p, h) (lds + 16384 + (p) * 16384 + (h) * 8192)

  if ((int)blockIdx.x >= gemm_blocks) {
    transpose_block(Wtr, WTtr, F_, D_, blockIdx.x - gemm_blocks, (void*)lds);
    return;
  }
  const int K = D_, NT = K >> 6, N = F_;
  const int cpx = gemm_blocks >> 3;
  const int bid = blockIdx.x;
  const int swzb = (bid & 7) * cpx + (bid >> 3);
  const int e = swzb / 160, rem = swzb % 160;
  const int m0 = (rem % 10) * 128, n0 = (rem / 10) * 256;   // n-major (L2)

  const u16* Ae = Aall + (size_t)e * MPE * K;
  const u16* Be = Btall + (size_t)e * N * K;

  const int tid = threadIdx.x;
  const int wv = tid >> 6, l = tid & 63;
  const int wr = wv >> 2, wc = wv & 3;
  const int lr = l & 15, lk = l >> 4;
  const int rswz = ((lr >> 3) & 1) << 4;
  const int gs0 = tid ^ (((tid >> 5) & 1) << 1);
  const size_t goffB = (size_t)((gs0 >> 2) & 127) * K + (size_t)((gs0 & 3) * 8);
  const size_t goffA = (size_t)((gs0 >> 2) & 63) * K
                     + (size_t)(((gs0 >> 8) & 1) * 32) + (size_t)((gs0 & 3) * 8);
  const int dwoff = wv * 512;

  const u16* pA0 = Ae + (size_t)m0 * K;
  const u16* pA1 = Ae + (size_t)(m0 + 64) * K;
  const u16* pB0 = Be + (size_t)n0 * K;
  const u16* pB1 = Be + (size_t)(n0 + 128) * K;

  f32x4 acc[4][4];
#pragma unroll
  for (int i = 0; i < 4; ++i)
#pragma unroll
    for (int j = 0; j < 4; ++j) acc[i][j] = (f32x4){0.f, 0.f, 0.f, 0.f};

  bf16x8 faA[2], faB[2], fb[8];

#define STAGE_A1(dhalf, rb, tt) \
    gload16((rb) + goffA + (size_t)((tt) * 64), (dhalf) + dwoff)

#define STAGE_B1(dhalf, rb, tt) do {                                       \
    const u16* s_ = (rb) + goffB + (size_t)((tt) * 64);                    \
    gload16(s_,      (dhalf) + dwoff);                                     \
    gload16(s_ + 32, (dhalf) + 4096 + dwoff);                              \
  } while (0)

#define READ_AQ1(q, p, fa_) do {                                           \
    _Pragma("unroll")                                                      \
    for (int kk = 0; kk < 2; ++kk)                                         \
      fa_[kk] = *(const bf16x8*)&LDA(p, wr)                                \
          [(kk*64 + (q)*16 + lr)*32 + ((lk*8) ^ rswz)];                    \
  } while (0)

#define READ_B_ALL1(p) do {                                                \
    _Pragma("unroll")                                                      \
    for (int nf = 0; nf < 4; ++nf)                                         \
      _Pragma("unroll")                                                    \
      for (int kk = 0; kk < 2; ++kk)                                       \
        fb[nf*2+kk] = *(const bf16x8*)&LDB(p, wc>>1)                       \
            [(kk*128 + (wc&1)*64 + (nf>>1)*32 + (nf&1)*16 + lr)*32         \
             + ((lk*8) ^ rswz)];                                           \
  } while (0)

#define MFMA_P1(q, fa_) do {                                               \
    __builtin_amdgcn_s_setprio(1);                                         \
    _Pragma("unroll")                                                      \
    for (int nf = 0; nf < 4; ++nf)                                         \
      _Pragma("unroll")                                                    \
      for (int kk = 0; kk < 2; ++kk)                                       \
        acc[q][nf] = __builtin_amdgcn_mfma_f32_16x16x32_bf16(              \
            fa_[kk], fb[nf*2+kk], acc[q][nf], 0, 0, 0);                    \
    __builtin_amdgcn_s_setprio(0);                                         \
  } while (0)

#define DO_T1(p, pn, tc) do {                                              \
    READ_AQ1(1, p, faB);                                                   \
    if ((tc) + 1 < NT) { STAGE_A1(LDA(pn,0), pA0, (tc)+1);                 \
                         STAGE_A1(LDA(pn,1), pA1, (tc)+1); }               \
    LGKMN(2); MFMA_P1(0, faA);                                             \
    READ_AQ1(2, p, faA);                                                   \
    LGKMN(2); MFMA_P1(1, faB);                                             \
    BAR();                                                                 \
    READ_AQ1(3, p, faB);                                                   \
    if ((tc) + 2 < NT) { STAGE_B1(LDB(p,0), pB0, (tc)+2);                  \
                         STAGE_B1(LDB(p,1), pB1, (tc)+2); }                \
    LGKMN(2); MFMA_P1(2, faA);                                             \
    LGKMN(0); MFMA_P1(3, faB);                                             \
    if ((tc) >= NT - 2) VMW(0); else VMW(4);                               \
    BAR();                                                                 \
    if ((tc) + 1 < NT) { READ_B_ALL1(pn); READ_AQ1(0, pn, faA); }          \
  } while (0)

  STAGE_A1(LDA(0,0), pA0, 0);
  STAGE_A1(LDA(0,1), pA1, 0);
  STAGE_B1(LDB(0,0), pB0, 0);
  STAGE_B1(LDB(0,1), pB1, 0);
  STAGE_B1(LDB(1,0), pB0, 1);
  STAGE_B1(LDB(1,1), pB1, 1);
  VMW(4); BAR();
  READ_B_ALL1(0); READ_AQ1(0, 0, faA);

  for (int t = 0; t < NT; t += 2) {
    DO_T1(0, 1, t);
    DO_T1(1, 0, t + 1);
  }

#pragma unroll
  for (int i = 0; i < 4; ++i) {
#pragma unroll
    for (int r = 0; r < 4; ++r) {
      const int grow = m0 + wr * 64 + i * 16 + lk * 4 + r;
      u16* hrow = hgout + ((size_t)e * MPE + grow) * (size_t)N + n0 + wc * 64;
#pragma unroll
      for (int j = 0; j < 4; ++j)
        hrow[j * 16 + lr] = f2bf(fmaxf(acc[i][j][r], 0.0f));
    }
  }
#undef LDA
#undef LDB
#undef STAGE_A1
#undef STAGE_B1
#undef READ_AQ1
#undef READ_B_ALL1
#undef MFMA_P1
#undef DO_T1
}

// ---------------------------------------------------------------------------
// GEMM2: out = maxp * (hg @ woT^T) scattered. Tile 256x256, BK=64,
// r8 read-ahead pipeline (lgkmcnt(4), vmcnt(4), 2 barriers/tile). Grid 160.
// Block order n-major within expert: 5 consecutive blocks share one 2MB
// woT panel (L2-hot) and stream A panels.
// ---------------------------------------------------------------------------
__global__ __launch_bounds__(512, 2) void moe_g2(
    const u16* __restrict__ Aall, const u16* __restrict__ Btall,
    float* __restrict__ out, const int* __restrict__ tok,
    const float* __restrict__ maxp)
{
  __shared__ __align__(16) u16 lds[2][2][2][8192]; // 128 KiB

  const int K = F_, NT = K >> 6, N = D_;
  const int gemm_blocks = 160, cpx = gemm_blocks >> 3;
  const int bid = blockIdx.x;
  const int swzb = (bid & 7) * cpx + (bid >> 3);
  const int e = swzb / 20, rem = swzb % 20;
  const int m0 = (rem % 5) * 256, n0 = (rem / 5) * 256;    // n-major (L2)

  const u16* Ae = Aall + (size_t)e * MPE * K;
  const u16* Be = Btall + (size_t)e * N * K;

  const int tid = threadIdx.x;
  const int wv = tid >> 6, l = tid & 63;
  const int wr = wv >> 2, wc = wv & 3;
  const int lr = l & 15, lk = l >> 4;
  const int rswz = ((lr >> 3) & 1) << 4;
  const int gs0 = tid ^ (((tid >> 5) & 1) << 1);
  const size_t goff = (size_t)((gs0 >> 2) & 127) * K + (size_t)((gs0 & 3) * 8);
  const int dwoff = wv * 512;

  const u16* pA0 = Ae + (size_t)m0 * K;
  const u16* pA1 = Ae + (size_t)(m0 + 128) * K;
  const u16* pB0 = Be + (size_t)n0 * K;
  const u16* pB1 = Be + (size_t)(n0 + 128) * K;

  f32x4 acc[8][4];
#pragma unroll
  for (int i = 0; i < 8; ++i)
#pragma unroll
    for (int j = 0; j < 4; ++j) acc[i][j] = (f32x4){0.f, 0.f, 0.f, 0.f};

  bf16x8 faA[4], faB[4], fb[8];

#define LDSH(p, ab, h) (&lds[p][ab][h][0])

#define STAGE2(dhalf, rb, tt) do {                                         \
    const u16* s_ = (rb) + goff + (size_t)((tt) * 64);                     \
    gload16(s_,      (dhalf) + dwoff);                                     \
    gload16(s_ + 32, (dhalf) + 4096 + dwoff);                              \
  } while (0)

#define READ_AQ2(q, p, fa_) do {                                           \
    _Pragma("unroll")                                                      \
    for (int mf = 0; mf < 2; ++mf)                                         \
      _Pragma("unroll")                                                    \
      for (int kk = 0; kk < 2; ++kk)                                       \
        fa_[mf*2+kk] = *(const bf16x8*)&lds[p][0][wr]                      \
            [(kk*128 + (q)*32 + mf*16 + lr)*32 + ((lk*8) ^ rswz)];         \
  } while (0)

#define READ_B_ALL2(p) do {                                                \
    _Pragma("unroll")                                                      \
    for (int nf = 0; nf < 4; ++nf)                                         \
      _Pragma("unroll")                                                    \
      for (int kk = 0; kk < 2; ++kk)                                       \
        fb[nf*2+kk] = *(const bf16x8*)&lds[p][1][wc>>1]                    \
            [(kk*128 + (wc&1)*64 + (nf>>1)*32 + (nf&1)*16 + lr)*32         \
             + ((lk*8) ^ rswz)];                                           \
  } while (0)

#define MFMA_P2(q, fa_) do {                                               \
    __builtin_amdgcn_s_setprio(1);                                         \
    _Pragma("unroll")                                                      \
    for (int mf = 0; mf < 2; ++mf)                                         \
      _Pragma("unroll")                                                    \
      for (int nf = 0; nf < 4; ++nf)                                       \
        _Pragma("unroll")                                                  \
        for (int kk = 0; kk < 2; ++kk)                                     \
          acc[(q)*2+mf][nf] = __builtin_amdgcn_mfma_f32_16x16x32_bf16(     \
              fa_[mf*2+kk], fb[nf*2+kk], acc[(q)*2+mf][nf], 0, 0, 0);      \
    __builtin_amdgcn_s_setprio(0);                                         \
  } while (0)

#define DO_T2(p, pn, tc) do {                                              \
    READ_AQ2(1, p, faB);                                                   \
    if ((tc) + 1 < NT) { STAGE2(LDSH(pn,0,0), pA0, (tc)+1);                \
                         STAGE2(LDSH(pn,0,1), pA1, (tc)+1); }              \
    LGKMN(4); MFMA_P2(0, faA);                                             \
    READ_AQ2(2, p, faA);                                                   \
    LGKMN(4); MFMA_P2(1, faB);                                             \
    BAR();                                                                 \
    READ_AQ2(3, p, faB);                                                   \
    if ((tc) + 2 < NT) { STAGE2(LDSH(p,1,0), pB0, (tc)+2);                 \
                         STAGE2(LDSH(p,1,1), pB1, (tc)+2); }               \
    LGKMN(4); MFMA_P2(2, faA);                                             \
    LGKMN(0); MFMA_P2(3, faB);                                             \
    if ((tc) >= NT - 2) VMW(0); else VMW(4);                               \
    BAR();                                                                 \
    if ((tc) + 1 < NT) { READ_B_ALL2(pn); READ_AQ2(0, pn, faA); }          \
  } while (0)

  STAGE2(LDSH(0,0,0), pA0, 0);
  STAGE2(LDSH(0,0,1), pA1, 0);
  STAGE2(LDSH(0,1,0), pB0, 0);
  STAGE2(LDSH(0,1,1), pB1, 0);
  STAGE2(LDSH(1,1,0), pB0, 1);
  STAGE2(LDSH(1,1,1), pB1, 1);
  VMW(4); BAR();
  READ_B_ALL2(0); READ_AQ2(0, 0, faA);

  for (int t = 0; t < NT; t += 2) {
    DO_T2(0, 1, t);
    DO_T2(1, 0, t + 1);
  }

#pragma unroll
  for (int i = 0; i < 8; ++i) {
#pragma unroll
    for (int r = 0; r < 4; ++r) {
      const int grow = m0 + wr * 128 + i * 16 + lk * 4 + r;
      const int b = grow / CAP_, c = grow % CAP_;
      const int t = tok[(b * E_ + e) * CAP_ + c];
      if (t >= 0) {
        const float sc = maxp[b * S_ + t];
        float* orow = out + ((size_t)(b * S_ + t)) * D_ + n0 + wc * 64;
#pragma unroll
        for (int j = 0; j < 4; ++j)
          orow[j * 16 + lr] = sc * acc[i][j][r];
      }
    }
  }
#undef LDSH
#undef STAGE2
#undef READ_AQ2
#undef READ_B_ALL2
#undef MFMA_P2
#undef DO_T2
}

// ---------------------------------------------------------------------------
extern "C" void kernel_launch(void* const* d_in, const int* in_sizes, int n_in,
                              void* d_out, int out_size, void* d_ws, size_t ws_size,
                              hipStream_t stream)
{
  const float* hs = (const float*)d_in[0];
  const float* rw = (const float*)d_in[1];
  const float* wi = (const float*)d_in[2];
  const float* wo = (const float*)d_in[3];

  float* out    = (float*)d_out;
  float* logits = out + (size_t)BS_ * D_;
  float* eout   = logits + (size_t)BS_ * E_;

  uint8_t* ws = (uint8_t*)d_ws;
  int*   tok  = (int*)(ws + 0);                 //   40,960 B
  float* maxp = (float*)(ws + 40960);           //   32,768 B
  int*   eidx = (int*)(ws + 73728);             //   32,768 B
  u16*   Xg   = (u16*)(ws + 131072);            // 20,971,520 B
  u16*   hg   = (u16*)(ws + 21102592);          // 83,886,080 B
  u16*   wiT  = (u16*)(ws + 104988672);         // 67,108,864 B
  if (ws_size < 172097536ULL) return;
  const bool big = ws_size >= 239206400ULL;
  u16* woT = big ? (u16*)(ws + 172097536) : wiT;

  const int twiT = E_ * (D_ / 128) * (F_ / 64);  // 4096 wi-transpose blocks
  const int twoT = E_ * (F_ / 128) * (D_ / 64);  // 4096 wo-transpose blocks
  const int g1 = E_ * (MPE / 128) * (F_ / 256);  // 1280 GEMM1 blocks (5 rounds)
  const int g2 = 160;                            // GEMM2 blocks

  prep_kernel<<<twiT + BS_ / 8, 512, 0, stream>>>(
      hs, rw, wi, wiT, logits, maxp, eidx, twiT);
  scan_kernel<<<B_ * E_, 256, 0, stream>>>(eidx, tok, eout, hs, maxp, out);
  gather_kernel<<<E_ * MPE, 256, 0, stream>>>(hs, tok, Xg);

  if (big) {
    moe_g1<<<g1 + twoT, 512, 0, stream>>>(Xg, wiT, hg, g1, wo, woT);
  } else {
    moe_g1<<<g1, 512, 0, stream>>>(Xg, wiT, hg, g1, nullptr, nullptr);
    transpose_kernel<<<twoT, 512, 0, stream>>>(wo, woT, F_, D_);
  }
  moe_g2<<<g2, 512, 0, stream>>>(hg, woT, out, tok, maxp);
}

// Round 12
// 325.788 us; speedup vs baseline: 1.1858x; 1.0033x over previous
//
#include <hip/hip_runtime.h>
#include <hip/hip_bf16.h>
#include <stdint.h>

#define B_ 4
#define S_ 2048
#define D_ 1024
#define F_ 4096
#define E_ 8
#define CAP_ 320
#define BS_ (B_*S_)      // 8192 tokens
#define MPE 1280         // B_*CAP_ rows per expert

typedef unsigned short u16;
typedef __attribute__((ext_vector_type(8))) short bf16x8;
typedef __attribute__((ext_vector_type(4))) float f32x4;
typedef __attribute__((ext_vector_type(4))) unsigned short u16x4;
typedef __attribute__((ext_vector_type(8))) unsigned short u16x8;

__device__ __forceinline__ u16 f2bf(float f) {
  union { float f; uint32_t u; } v; v.f = f;
  uint32_t r = (v.u + 0x7FFFu + ((v.u >> 16) & 1u)) >> 16;
  return (u16)r;
}

__device__ __forceinline__ void gload16(const void* g, void* l) {
  __builtin_amdgcn_global_load_lds(
      (const __attribute__((address_space(1))) uint32_t*)g,
      (__attribute__((address_space(3))) uint32_t*)l, 16, 0, 0);
}

// ---------------------------------------------------------------------------
// Transpose+convert block (512 threads): W[e][K][N] f32 -> WT[e][N][K] bf16.
// Tile = 128 K-rows x 64 N-cols.
// ---------------------------------------------------------------------------
__device__ __forceinline__ void transpose_block(
    const float* __restrict__ W, u16* __restrict__ WT,
    const int K, const int N, const int bid, void* ldsraw)
{
  float (*tile)[65] = (float(*)[65])ldsraw;
  const int tk = K >> 7, tn = N >> 6;
  const int e = bid / (tk * tn), r = bid % (tk * tn);
  const int k0 = (r / tn) << 7, n0 = (r % tn) << 6;
  const float* We = W + (size_t)e * K * N;
  u16* WTe = WT + (size_t)e * N * K;
  const int t = threadIdx.x;
  const int fr = t >> 2, c0 = (t & 3) * 16;
#pragma unroll
  for (int j = 0; j < 4; ++j) {
    const float4 v = *(const float4*)(We + (size_t)(k0 + fr) * N + n0 + c0 + j * 4);
    tile[fr][c0 + j*4 + 0] = v.x; tile[fr][c0 + j*4 + 1] = v.y;
    tile[fr][c0 + j*4 + 2] = v.z; tile[fr][c0 + j*4 + 3] = v.w;
  }
  __syncthreads();
  const int nr = t >> 3, kk0 = (t & 7) * 16;
  u16x8 o0, o1;
#pragma unroll
  for (int j = 0; j < 8; ++j) o0[j] = f2bf(tile[kk0 + j][nr]);
#pragma unroll
  for (int j = 0; j < 8; ++j) o1[j] = f2bf(tile[kk0 + 8 + j][nr]);
  u16* dst = WTe + (size_t)(n0 + nr) * K + k0 + kk0;
  *(u16x8*)dst = o0;
  *(u16x8*)(dst + 8) = o1;
}

__global__ __launch_bounds__(512) void transpose_kernel(
    const float* __restrict__ W, u16* __restrict__ WT, const int K, const int N)
{
  __shared__ __align__(16) float tile[128][65];
  transpose_block(W, WT, K, N, blockIdx.x, (void*)tile);
}

// ---------------------------------------------------------------------------
// Prep: blocks [0,twiT) = wi transpose; rest = router (8 tokens/block).
// ---------------------------------------------------------------------------
__global__ __launch_bounds__(512) void prep_kernel(
    const float* __restrict__ hs, const float* __restrict__ rw,
    const float* __restrict__ wi, u16* __restrict__ wT,
    float* __restrict__ logits, float* __restrict__ maxp,
    int* __restrict__ eidx, const int twiT)
{
  __shared__ __align__(16) float tile[128][65];
  if ((int)blockIdx.x < twiT) {
    transpose_block(wi, wT, D_, F_, blockIdx.x, (void*)tile);
    return;
  }
  const int wv = threadIdx.x >> 6, l = threadIdx.x & 63;
  const int token = (blockIdx.x - twiT) * 8 + wv;
  const float* row = hs + (size_t)token * D_;
  const float4* rw4 = (const float4*)rw;

  double acc0=0, acc1=0, acc2=0, acc3=0, acc4=0, acc5=0, acc6=0, acc7=0;
#pragma unroll
  for (int j = 0; j < 4; ++j) {
    const int d4 = l + j * 64;
    const float4 v = ((const float4*)row)[d4];
#pragma unroll
    for (int c = 0; c < 4; ++c) {
      const int d = d4 * 4 + c;
      const float x = (&v.x)[c];
      const float4 w0 = rw4[d * 2];
      const float4 w1 = rw4[d * 2 + 1];
      acc0 += (double)x * (double)w0.x;
      acc1 += (double)x * (double)w0.y;
      acc2 += (double)x * (double)w0.z;
      acc3 += (double)x * (double)w0.w;
      acc4 += (double)x * (double)w1.x;
      acc5 += (double)x * (double)w1.y;
      acc6 += (double)x * (double)w1.z;
      acc7 += (double)x * (double)w1.w;
    }
  }
  double acc[E_] = {acc0, acc1, acc2, acc3, acc4, acc5, acc6, acc7};
#pragma unroll
  for (int e = 0; e < E_; ++e) {
#pragma unroll
    for (int off = 32; off; off >>= 1)
      acc[e] += __shfl_xor(acc[e], off);
  }
  if (l == 0) {
    float lg[E_];
#pragma unroll
    for (int e = 0; e < E_; ++e) lg[e] = (float)acc[e];
    float lmax = lg[0]; int am = 0;
#pragma unroll
    for (int e = 1; e < E_; ++e) { if (lg[e] > lmax) { lmax = lg[e]; am = e; } }
    float sum = 0.f;
#pragma unroll
    for (int e = 0; e < E_; ++e) sum += expf(lg[e] - lmax);
#pragma unroll
    for (int e = 0; e < E_; ++e) logits[(size_t)token * E_ + e] = lg[e];
    maxp[token] = 1.0f / sum;
    eidx[token] = am;
  }
}

// ---------------------------------------------------------------------------
// Capacity scan: one block per (b,e). Also: tok init (-1), eout, and
// out rows for DROPPED tokens (out = maxp * hs).
// ---------------------------------------------------------------------------
__global__ __launch_bounds__(256) void scan_kernel(
    const int* __restrict__ eidx, int* __restrict__ tok,
    float* __restrict__ eout, const float* __restrict__ hs,
    const float* __restrict__ maxp, float* __restrict__ out)
{
  const int b = blockIdx.x >> 3, e = blockIdx.x & 7;
  __shared__ int wsum[4];
  const int tid = threadIdx.x, wv = tid >> 6, l = tid & 63;
  for (int i = tid; i < CAP_; i += 256) tok[(b * E_ + e) * CAP_ + i] = -1;
  __syncthreads();
  int base = 0;
  for (int ch = 0; ch < S_ / 256; ++ch) {
    const int s = ch * 256 + tid;
    const bool p = (eidx[b * S_ + s] == e);
    const unsigned long long m = __ballot(p);
    const int lp = __popcll(m & ((1ULL << l) - 1ULL));
    if (l == 0) wsum[wv] = __popcll(m);
    __syncthreads();
    int pre = 0, tot = 0;
#pragma unroll
    for (int w = 0; w < 4; ++w) { if (w < wv) pre += wsum[w]; tot += wsum[w]; }
    if (p) {
      const int rank = base + pre + lp;
      if (rank < CAP_) {
        tok[(b * E_ + e) * CAP_ + rank] = s;
        eout[b * S_ + s] = (float)e;
      } else {
        eout[b * S_ + s] = 0.0f;
        const float mp = maxp[b * S_ + s];
        const float4* src = (const float4*)(hs + (size_t)(b * S_ + s) * D_);
        float4* dst = (float4*)(out + (size_t)(b * S_ + s) * D_);
        for (int j = 0; j < D_ / 4; ++j) {
          const float4 vv = src[j];
          float4 o; o.x = vv.x * mp; o.y = vv.y * mp; o.z = vv.z * mp; o.w = vv.w * mp;
          dst[j] = o;
        }
      }
    }
    base += tot;
    __syncthreads();
  }
}

// ---------------------------------------------------------------------------
// Gather routed tokens -> Xg[e][b*CAP+c][D] bf16 (zeros for empty slots)
// ---------------------------------------------------------------------------
__global__ __launch_bounds__(256) void gather_kernel(
    const float* __restrict__ hs, const int* __restrict__ tok,
    u16* __restrict__ Xg)
{
  const int bx = blockIdx.x;
  const int e = bx / MPE, r = bx % MPE;
  const int b = r / CAP_, c = r % CAP_;
  const int t = tok[(b * E_ + e) * CAP_ + c];
  const int d = threadIdx.x * 4;
  u16x4 o;
  if (t >= 0) {
    const float4 vv = *(const float4*)(hs + ((size_t)(b * S_ + t)) * D_ + d);
    o[0] = f2bf(vv.x); o[1] = f2bf(vv.y); o[2] = f2bf(vv.z); o[3] = f2bf(vv.w);
  } else {
    o[0] = 0; o[1] = 0; o[2] = 0; o[3] = 0;
  }
  *(u16x4*)(Xg + (size_t)bx * D_ + d) = o;
}

// ---------------------------------------------------------------------------
// Shared GEMM helper macros. NOTE: no manual lgkmcnt waits in the K-loops —
// fragment reads are compiler-visible loads, so hipcc inserts fine-grained
// lgkmcnt itself (m97 mode). Manual waits + sched_barrier(0) split the
// scheduling regions and were costing ~20% (m141 failure mode).
// ---------------------------------------------------------------------------
#define BAR() __builtin_amdgcn_s_barrier()
#define VMW(n) asm volatile("s_waitcnt vmcnt(" #n ")" ::: "memory")

// ---------------------------------------------------------------------------
// GEMM1: hg = relu(Xg @ wiT^T). Tile 128x256, BK=64, 8 waves (2Mx4N),
// 96 KiB LDS, grid 1280 (+ fused wo-transpose into DISJOINT woT).
// n-major block order within expert (L2 panel reuse, r11-proven).
// ---------------------------------------------------------------------------
__global__ __launch_bounds__(512, 2) void moe_g1(
    const u16* __restrict__ Aall, const u16* __restrict__ Btall,
    u16* __restrict__ hgout, const int gemm_blocks,
    const float* __restrict__ Wtr, u16* __restrict__ WTtr)
{
  __shared__ __align__(16) u16 lds[49152];   // 96 KiB

#define LDA(p, h) (lds + (p) * 8192 + (h) * 4096)
#define LDB(p, h) (lds + 16384 + (p) * 16384 + (h) * 8192)

  if ((int)blockIdx.x >= gemm_blocks) {
    transpose_block(Wtr, WTtr, F_, D_, blockIdx.x - gemm_blocks, (void*)lds);
    return;
  }
  const int K = D_, NT = K >> 6, N = F_;
  const int cpx = gemm_blocks >> 3;
  const int bid = blockIdx.x;
  const int swzb = (bid & 7) * cpx + (bid >> 3);
  const int e = swzb / 160, rem = swzb % 160;
  const int m0 = (rem % 10) * 128, n0 = (rem / 10) * 256;   // n-major (L2)

  const u16* Ae = Aall + (size_t)e * MPE * K;
  const u16* Be = Btall + (size_t)e * N * K;

  const int tid = threadIdx.x;
  const int wv = tid >> 6, l = tid & 63;
  const int wr = wv >> 2, wc = wv & 3;
  const int lr = l & 15, lk = l >> 4;
  const int rswz = ((lr >> 3) & 1) << 4;
  const int gs0 = tid ^ (((tid >> 5) & 1) << 1);
  const size_t goffB = (size_t)((gs0 >> 2) & 127) * K + (size_t)((gs0 & 3) * 8);
  const size_t goffA = (size_t)((gs0 >> 2) & 63) * K
                     + (size_t)(((gs0 >> 8) & 1) * 32) + (size_t)((gs0 & 3) * 8);
  const int dwoff = wv * 512;

  const u16* pA0 = Ae + (size_t)m0 * K;
  const u16* pA1 = Ae + (size_t)(m0 + 64) * K;
  const u16* pB0 = Be + (size_t)n0 * K;
  const u16* pB1 = Be + (size_t)(n0 + 128) * K;

  f32x4 acc[4][4];
#pragma unroll
  for (int i = 0; i < 4; ++i)
#pragma unroll
    for (int j = 0; j < 4; ++j) acc[i][j] = (f32x4){0.f, 0.f, 0.f, 0.f};

  bf16x8 faA[2], faB[2], fb[8];

#define STAGE_A1(dhalf, rb, tt) \
    gload16((rb) + goffA + (size_t)((tt) * 64), (dhalf) + dwoff)

#define STAGE_B1(dhalf, rb, tt) do {                                       \
    const u16* s_ = (rb) + goffB + (size_t)((tt) * 64);                    \
    gload16(s_,      (dhalf) + dwoff);                                     \
    gload16(s_ + 32, (dhalf) + 4096 + dwoff);                              \
  } while (0)

#define READ_AQ1(q, p, fa_) do {                                           \
    _Pragma("unroll")                                                      \
    for (int kk = 0; kk < 2; ++kk)                                         \
      fa_[kk] = *(const bf16x8*)&LDA(p, wr)                                \
          [(kk*64 + (q)*16 + lr)*32 + ((lk*8) ^ rswz)];                    \
  } while (0)

#define READ_B_ALL1(p) do {                                                \
    _Pragma("unroll")                                                      \
    for (int nf = 0; nf < 4; ++nf)                                         \
      _Pragma("unroll")                                                    \
      for (int kk = 0; kk < 2; ++kk)                                       \
        fb[nf*2+kk] = *(const bf16x8*)&LDB(p, wc>>1)                       \
            [(kk*128 + (wc&1)*64 + (nf>>1)*32 + (nf&1)*16 + lr)*32         \
             + ((lk*8) ^ rswz)];                                           \
  } while (0)

#define MFMA_P1(q, fa_) do {                                               \
    __builtin_amdgcn_s_setprio(1);                                         \
    _Pragma("unroll")                                                      \
    for (int nf = 0; nf < 4; ++nf)                                         \
      _Pragma("unroll")                                                    \
      for (int kk = 0; kk < 2; ++kk)                                       \
        acc[q][nf] = __builtin_amdgcn_mfma_f32_16x16x32_bf16(              \
            fa_[kk], fb[nf*2+kk], acc[q][nf], 0, 0, 0);                    \
    __builtin_amdgcn_s_setprio(0);                                         \
  } while (0)

#define DO_T1(p, pn, tc) do {                                              \
    READ_AQ1(1, p, faB);                                                   \
    if ((tc) + 1 < NT) { STAGE_A1(LDA(pn,0), pA0, (tc)+1);                 \
                         STAGE_A1(LDA(pn,1), pA1, (tc)+1); }               \
    MFMA_P1(0, faA);                                                       \
    READ_AQ1(2, p, faA);                                                   \
    MFMA_P1(1, faB);                                                       \
    BAR();                                                                 \
    READ_AQ1(3, p, faB);                                                   \
    if ((tc) + 2 < NT) { STAGE_B1(LDB(p,0), pB0, (tc)+2);                  \
                         STAGE_B1(LDB(p,1), pB1, (tc)+2); }                \
    MFMA_P1(2, faA);                                                       \
    MFMA_P1(3, faB);                                                       \
    if ((tc) >= NT - 2) VMW(0); else VMW(4);                               \
    BAR();                                                                 \
    if ((tc) + 1 < NT) { READ_B_ALL1(pn); READ_AQ1(0, pn, faA); }          \
  } while (0)

  STAGE_A1(LDA(0,0), pA0, 0);
  STAGE_A1(LDA(0,1), pA1, 0);
  STAGE_B1(LDB(0,0), pB0, 0);
  STAGE_B1(LDB(0,1), pB1, 0);
  STAGE_B1(LDB(1,0), pB0, 1);
  STAGE_B1(LDB(1,1), pB1, 1);
  VMW(4); BAR();
  READ_B_ALL1(0); READ_AQ1(0, 0, faA);

  for (int t = 0; t < NT; t += 2) {
    DO_T1(0, 1, t);
    DO_T1(1, 0, t + 1);
  }

#pragma unroll
  for (int i = 0; i < 4; ++i) {
#pragma unroll
    for (int r = 0; r < 4; ++r) {
      const int grow = m0 + wr * 64 + i * 16 + lk * 4 + r;
      u16* hrow = hgout + ((size_t)e * MPE + grow) * (size_t)N + n0 + wc * 64;
#pragma unroll
      for (int j = 0; j < 4; ++j)
        hrow[j * 16 + lr] = f2bf(fmaxf(acc[i][j][r], 0.0f));
    }
  }
#undef LDA
#undef LDB
#undef STAGE_A1
#undef STAGE_B1
#undef READ_AQ1
#undef READ_B_ALL1
#undef MFMA_P1
#undef DO_T1
}

// ---------------------------------------------------------------------------
// GEMM2: out = maxp * (hg @ woT^T) scattered. Tile 256x256, BK=64,
// read-ahead pipeline (compiler lgkm waits, vmcnt(4), 2 barriers/tile).
// Grid 160, n-major block order (L2 panel reuse).
// ---------------------------------------------------------------------------
__global__ __launch_bounds__(512, 2) void moe_g2(
    const u16* __restrict__ Aall, const u16* __restrict__ Btall,
    float* __restrict__ out, const int* __restrict__ tok,
    const float* __restrict__ maxp)
{
  __shared__ __align__(16) u16 lds[2][2][2][8192]; // 128 KiB

  const int K = F_, NT = K >> 6, N = D_;
  const int gemm_blocks = 160, cpx = gemm_blocks >> 3;
  const int bid = blockIdx.x;
  const int swzb = (bid & 7) * cpx + (bid >> 3);
  const int e = swzb / 20, rem = swzb % 20;
  const int m0 = (rem % 5) * 256, n0 = (rem / 5) * 256;    // n-major (L2)

  const u16* Ae = Aall + (size_t)e * MPE * K;
  const u16* Be = Btall + (size_t)e * N * K;

  const int tid = threadIdx.x;
  const int wv = tid >> 6, l = tid & 63;
  const int wr = wv >> 2, wc = wv & 3;
  const int lr = l & 15, lk = l >> 4;
  const int rswz = ((lr >> 3) & 1) << 4;
  const int gs0 = tid ^ (((tid >> 5) & 1) << 1);
  const size_t goff = (size_t)((gs0 >> 2) & 127) * K + (size_t)((gs0 & 3) * 8);
  const int dwoff = wv * 512;

  const u16* pA0 = Ae + (size_t)m0 * K;
  const u16* pA1 = Ae + (size_t)(m0 + 128) * K;
  const u16* pB0 = Be + (size_t)n0 * K;
  const u16* pB1 = Be + (size_t)(n0 + 128) * K;

  f32x4 acc[8][4];
#pragma unroll
  for (int i = 0; i < 8; ++i)
#pragma unroll
    for (int j = 0; j < 4; ++j) acc[i][j] = (f32x4){0.f, 0.f, 0.f, 0.f};

  bf16x8 faA[4], faB[4], fb[8];

#define LDSH(p, ab, h) (&lds[p][ab][h][0])

#define STAGE2(dhalf, rb, tt) do {                                         \
    const u16* s_ = (rb) + goff + (size_t)((tt) * 64);                     \
    gload16(s_,      (dhalf) + dwoff);                                     \
    gload16(s_ + 32, (dhalf) + 4096 + dwoff);                              \
  } while (0)

#define READ_AQ2(q, p, fa_) do {                                           \
    _Pragma("unroll")                                                      \
    for (int mf = 0; mf < 2; ++mf)                                         \
      _Pragma("unroll")                                                    \
      for (int kk = 0; kk < 2; ++kk)                                       \
        fa_[mf*2+kk] = *(const bf16x8*)&lds[p][0][wr]                      \
            [(kk*128 + (q)*32 + mf*16 + lr)*32 + ((lk*8) ^ rswz)];         \
  } while (0)

#define READ_B_ALL2(p) do {                                                \
    _Pragma("unroll")                                                      \
    for (int nf = 0; nf < 4; ++nf)                                         \
      _Pragma("unroll")                                                    \
      for (int kk = 0; kk < 2; ++kk)                                       \
        fb[nf*2+kk] = *(const bf16x8*)&lds[p][1][wc>>1]                    \
            [(kk*128 + (wc&1)*64 + (nf>>1)*32 + (nf&1)*16 + lr)*32         \
             + ((lk*8) ^ rswz)];                                           \
  } while (0)

#define MFMA_P2(q, fa_) do {                                               \
    __builtin_amdgcn_s_setprio(1);                                         \
    _Pragma("unroll")                                                      \
    for (int mf = 0; mf < 2; ++mf)                                         \
      _Pragma("unroll")                                                    \
      for (int nf = 0; nf < 4; ++nf)                                       \
        _Pragma("unroll")                                                  \
        for (int kk = 0; kk < 2; ++kk)                                     \
          acc[(q)*2+mf][nf] = __builtin_amdgcn_mfma_f32_16x16x32_bf16(     \
              fa_[mf*2+kk], fb[nf*2+kk], acc[(q)*2+mf][nf], 0, 0, 0);      \
    __builtin_amdgcn_s_setprio(0);                                         \
  } while (0)

#define DO_T2(p, pn, tc) do {                                              \
    READ_AQ2(1, p, faB);                                                   \
    if ((tc) + 1 < NT) { STAGE2(LDSH(pn,0,0), pA0, (tc)+1);                \
                         STAGE2(LDSH(pn,0,1), pA1, (tc)+1); }              \
    MFMA_P2(0, faA);                                                       \
    READ_AQ2(2, p, faA);                                                   \
    MFMA_P2(1, faB);                                                       \
    BAR();                                                                 \
    READ_AQ2(3, p, faB);                                                   \
    if ((tc) + 2 < NT) { STAGE2(LDSH(p,1,0), pB0, (tc)+2);                 \
                         STAGE2(LDSH(p,1,1), pB1, (tc)+2); }               \
    MFMA_P2(2, faA);                                                       \
    MFMA_P2(3, faB);                                                       \
    if ((tc) >= NT - 2) VMW(0); else VMW(4);                               \
    BAR();                                                                 \
    if ((tc) + 1 < NT) { READ_B_ALL2(pn); READ_AQ2(0, pn, faA); }          \
  } while (0)

  STAGE2(LDSH(0,0,0), pA0, 0);
  STAGE2(LDSH(0,0,1), pA1, 0);
  STAGE2(LDSH(0,1,0), pB0, 0);
  STAGE2(LDSH(0,1,1), pB1, 0);
  STAGE2(LDSH(1,1,0), pB0, 1);
  STAGE2(LDSH(1,1,1), pB1, 1);
  VMW(4); BAR();
  READ_B_ALL2(0); READ_AQ2(0, 0, faA);

  for (int t = 0; t < NT; t += 2) {
    DO_T2(0, 1, t);
    DO_T2(1, 0, t + 1);
  }

#pragma unroll
  for (int i = 0; i < 8; ++i) {
#pragma unroll
    for (int r = 0; r < 4; ++r) {
      const int grow = m0 + wr * 128 + i * 16 + lk * 4 + r;
      const int b = grow / CAP_, c = grow % CAP_;
      const int t = tok[(b * E_ + e) * CAP_ + c];
      if (t >= 0) {
        const float sc = maxp[b * S_ + t];
        float* orow = out + ((size_t)(b * S_ + t)) * D_ + n0 + wc * 64;
#pragma unroll
        for (int j = 0; j < 4; ++j)
          orow[j * 16 + lr] = sc * acc[i][j][r];
      }
    }
  }
#undef LDSH
#undef STAGE2
#undef READ_AQ2
#undef READ_B_ALL2
#undef MFMA_P2
#undef DO_T2
}

// ---------------------------------------------------------------------------
extern "C" void kernel_launch(void* const* d_in, const int* in_sizes, int n_in,
                              void* d_out, int out_size, void* d_ws, size_t ws_size,
                              hipStream_t stream)
{
  const float* hs = (const float*)d_in[0];
  const float* rw = (const float*)d_in[1];
  const float* wi = (const float*)d_in[2];
  const float* wo = (const float*)d_in[3];

  float* out    = (float*)d_out;
  float* logits = out + (size_t)BS_ * D_;
  float* eout   = logits + (size_t)BS_ * E_;

  uint8_t* ws = (uint8_t*)d_ws;
  int*   tok  = (int*)(ws + 0);                 //   40,960 B
  float* maxp = (float*)(ws + 40960);           //   32,768 B
  int*   eidx = (int*)(ws + 73728);             //   32,768 B
  u16*   Xg   = (u16*)(ws + 131072);            // 20,971,520 B
  u16*   hg   = (u16*)(ws + 21102592);          // 83,886,080 B
  u16*   wiT  = (u16*)(ws + 104988672);         // 67,108,864 B
  if (ws_size < 172097536ULL) return;
  const bool big = ws_size >= 239206400ULL;
  u16* woT = big ? (u16*)(ws + 172097536) : wiT;

  const int twiT = E_ * (D_ / 128) * (F_ / 64);  // 4096 wi-transpose blocks
  const int twoT = E_ * (F_ / 128) * (D_ / 64);  // 4096 wo-transpose blocks
  const int g1 = E_ * (MPE / 128) * (F_ / 256);  // 1280 GEMM1 blocks (5 rounds)
  const int g2 = 160;                            // GEMM2 blocks

  prep_kernel<<<twiT + BS_ / 8, 512, 0, stream>>>(
      hs, rw, wi, wiT, logits, maxp, eidx, twiT);
  scan_kernel<<<B_ * E_, 256, 0, stream>>>(eidx, tok, eout, hs, maxp, out);
  gather_kernel<<<E_ * MPE, 256, 0, stream>>>(hs, tok, Xg);

  if (big) {
    moe_g1<<<g1 + twoT, 512, 0, stream>>>(Xg, wiT, hg, g1, wo, woT);
  } else {
    moe_g1<<<g1, 512, 0, stream>>>(Xg, wiT, hg, g1, nullptr, nullptr);
    transpose_kernel<<<twoT, 512, 0, stream>>>(wo, woT, F_, D_);
  }
  moe_g2<<<g2, 512, 0, stream>>>(hg, woT, out, tok, maxp);
}